// Round 1
// 213.334 us; speedup vs baseline: 1.1223x; 1.1223x over previous
//
#include <hip/hip_runtime.h>
#include <math.h>

#define HH 4      // heads
#define DD 32     // out dim per head
#define HD 128    // H*D
#define INF 128   // node in_dim
#define EDF 64    // edge feat dim
#define NEG 0.01f
#define NB 256    // scan blocks
#define ONODES 64 // nodes per k_out block

// ---- precompute collapsed weight matrices -------------------------------
// blocks 0..15  : WeWo[(h*64+k)*32+o] = sum_d We[k][h*32+d]*Wo[h*32+d][o]
// blocks 16..23 : WnWo[k*32+o]        = sum_d Wn[k][d']*Wo[d'][o]
// block  24     : WnA/WnB[k][h] (Wn·Wa halves), WeC[k][h] (We·(Wa_lo+Wa_hi))
__global__ void k_pre(const float* __restrict__ Wn, const float* __restrict__ We,
                      const float* __restrict__ Wa, const float* __restrict__ Wo,
                      float* __restrict__ WnA, float* __restrict__ WnB,
                      float* __restrict__ WeC, float* __restrict__ WeWo,
                      float* __restrict__ WnWo) {
    int b = blockIdx.x, tid = threadIdx.x;   // 25 blocks x 512
    if (b < 16) {
        int t = b * 512 + tid;               // t = (h*64+k)*32 + o
        int j = t >> 5, o = t & 31;
        int h = j >> 6, k = j & 63;
        float a = 0.f;
        for (int d = 0; d < DD; ++d)
            a += We[k * HD + h * DD + d] * Wo[(h * DD + d) * DD + o];
        WeWo[t] = a;
    } else if (b < 24) {
        int u = (b - 16) * 512 + tid;        // u = k*32 + o
        int k = u >> 5, o = u & 31;
        float a = 0.f;
        for (int d = 0; d < HD; ++d)
            a += Wn[k * HD + d] * Wo[d * DD + o];
        WnWo[u] = a;
    } else {
        int k = tid >> 2, h = tid & 3;
        float a = 0.f, bb = 0.f;
        for (int d = 0; d < DD; ++d) {
            float w = Wn[k * HD + h * DD + d];
            a += w * Wa[d];
            bb += w * Wa[DD + d];
        }
        WnA[k * HH + h] = a;
        WnB[k * HH + h] = bb;
        if (k < EDF) {
            float c = 0.f;
            for (int d = 0; d < DD; ++d)
                c += We[k * HD + h * DD + d] * (Wa[d] + Wa[DD + d]);
            WeC[k * HH + h] = c;
        }
    }
}

// ---- per-node attention scalars an,bn (wave per node) -------------------
__global__ void k_nodes(const float* __restrict__ X, const float* __restrict__ WnA,
                        const float* __restrict__ WnB, float* __restrict__ an,
                        float* __restrict__ bn, int N) {
    int wave = threadIdx.x >> 6, lane = threadIdx.x & 63;
    int n = blockIdx.x * 4 + wave;
    if (n >= N) return;
    float x0 = X[(size_t)n * INF + lane];
    float x1 = X[(size_t)n * INF + 64 + lane];
    float pa[HH], pb[HH];
#pragma unroll
    for (int h = 0; h < HH; ++h) {
        pa[h] = x0 * WnA[lane * HH + h] + x1 * WnA[(lane + 64) * HH + h];
        pb[h] = x0 * WnB[lane * HH + h] + x1 * WnB[(lane + 64) * HH + h];
    }
#pragma unroll
    for (int off = 32; off; off >>= 1)
#pragma unroll
        for (int h = 0; h < HH; ++h) {
            pa[h] += __shfl_xor(pa[h], off);
            pb[h] += __shfl_xor(pb[h], off);
        }
    if (lane == 0)
#pragma unroll
        for (int h = 0; h < HH; ++h) {
            an[(size_t)n * HH + h] = pa[h];
            bn[(size_t)n * HH + h] = pb[h];
        }
}

// ---- CSR build ----------------------------------------------------------
__global__ void k_init(int* __restrict__ deg, int N) {
    int i = blockIdx.x * blockDim.x + threadIdx.x;
    if (i < N) deg[i] = 0;
}
__global__ void k_hist(const int* __restrict__ dst, int* __restrict__ deg,
                       int* __restrict__ rank, int E) {
    int e = blockIdx.x * blockDim.x + threadIdx.x;
    if (e < E) rank[e] = atomicAdd(&deg[dst[e]], 1);
}
__global__ void k_scan1(const int* __restrict__ deg, int* __restrict__ partial,
                        int N, int chunk) {
    __shared__ int s[256];
    int tid = threadIdx.x;
    int i = blockIdx.x * chunk + tid;
    int v = (tid < chunk && i < N) ? deg[i] : 0;
    s[tid] = v; __syncthreads();
    for (int off = 128; off; off >>= 1) {
        if (tid < off) s[tid] += s[tid + off];
        __syncthreads();
    }
    if (tid == 0) partial[blockIdx.x] = s[0];
}
__global__ void k_scan2(const int* __restrict__ partial, int* __restrict__ pscan) {
    __shared__ int s[NB];
    int tid = threadIdx.x;
    int v = partial[tid];
    s[tid] = v; __syncthreads();
    for (int off = 1; off < NB; off <<= 1) {
        int t = (tid >= off) ? s[tid - off] : 0;
        __syncthreads();
        s[tid] += t;
        __syncthreads();
    }
    pscan[tid] = s[tid] - v;   // exclusive
}
__global__ void k_scan3(const int* __restrict__ deg, const int* __restrict__ pscan,
                        int* __restrict__ offs, int N, int chunk) {
    __shared__ int s[256];
    int tid = threadIdx.x;
    int i = blockIdx.x * chunk + tid;
    int v = (tid < chunk && i < N) ? deg[i] : 0;
    s[tid] = v; __syncthreads();
    for (int off = 1; off < 256; off <<= 1) {
        int t = (tid >= off) ? s[tid - off] : 0;
        __syncthreads();
        s[tid] += t;
        __syncthreads();
    }
    if (tid < chunk && i < N)
        offs[i] = pscan[blockIdx.x] + s[tid] - v;   // exclusive
}
__global__ void k_eids(const int* __restrict__ dst, const int* __restrict__ offs,
                       const int* __restrict__ rank, int* __restrict__ eids, int E) {
    int e = blockIdx.x * blockDim.x + threadIdx.x;
    if (e < E) eids[offs[dst[e]] + rank[e]] = e;
}

// ---- fused logits + softmax + aggregate (wave per node, 4 edges/iter) ---
// lane = g*16+q; group g handles edge (i*4+g); lane q holds EF chunk [4q..4q+3]
// Software-pipelined: eids prefetched 2 iters ahead, EF/an gathers issued
// 1 iter ahead (double-buffered in regs) so compute(i) overlaps loads(i+1).
__global__ void k_agg(const float* __restrict__ EF, const float* __restrict__ an,
                      const float* __restrict__ bn, const float* __restrict__ WeC,
                      const int* __restrict__ src, const int* __restrict__ eids,
                      const int* __restrict__ offs, const int* __restrict__ deg,
                      float* __restrict__ Ghat, int N) {
    __shared__ float wec_s[EDF * HH];
    if (threadIdx.x < EDF * HH) wec_s[threadIdx.x] = WeC[threadIdx.x];
    __syncthreads();
    int wave = threadIdx.x >> 6, lane = threadIdx.x & 63;
    int g = lane >> 4, q = lane & 15;
    int n = blockIdx.x * 4 + wave;
    if (n >= N) return;
    int dn = deg[n];
    if (dn == 0) return;                     // k_out falls back to Wn path
    int st = offs[n];
    int dn1 = dn - 1;

    float wc[4][4];                          // WeC[q*4+c][h]
#pragma unroll
    for (int c = 0; c < 4; ++c)
#pragma unroll
        for (int h = 0; h < 4; ++h)
            wc[c][h] = wec_s[(q * 4 + c) * 4 + h];
    float4 bn4 = *(const float4*)(bn + (size_t)n * HH);

    float sh[4] = {0.f, 0.f, 0.f, 0.f};
    float gacc[4][4] = {};                   // [h][c]
    int nb = (dn + 3) >> 2;

    // pipeline prologue: eids for iters 0 and 1, gathers for iter 0
    int r0 = g;
    int eA = eids[st + (r0 < dn ? r0 : dn1)];
    int r1 = 4 + g;
    int eB = eids[st + (r1 < dn ? r1 : dn1)];
    float4 x4A = *(const float4*)(EF + (size_t)eA * EDF + q * 4);
    float4 anA = *(const float4*)(an + (size_t)src[eA] * HH);

    for (int i = 0; i < nb; ++i) {
        // issue next iteration's gathers + eids 2 ahead BEFORE computing
        float4 x4B = *(const float4*)(EF + (size_t)eB * EDF + q * 4);
        float4 anB = *(const float4*)(an + (size_t)src[eB] * HH);
        int r2 = (i + 2) * 4 + g;
        int eC = eids[st + (r2 < dn ? r2 : dn1)];

        bool valid = (i * 4 + g) < dn;
        float ae[4];
#pragma unroll
        for (int h = 0; h < 4; ++h)
            ae[h] = x4A.x * wc[0][h] + x4A.y * wc[1][h] + x4A.z * wc[2][h] + x4A.w * wc[3][h];
#pragma unroll
        for (int off = 1; off < 16; off <<= 1)
#pragma unroll
            for (int h = 0; h < 4; ++h)
                ae[h] += __shfl_xor(ae[h], off);
        float lg[4];
        lg[0] = anA.x + bn4.x + ae[0];
        lg[1] = anA.y + bn4.y + ae[1];
        lg[2] = anA.z + bn4.z + ae[2];
        lg[3] = anA.w + bn4.w + ae[3];
#pragma unroll
        for (int h = 0; h < 4; ++h) {
            float l = lg[h];
            float w = valid ? __expf(l > 0.f ? l : NEG * l) : 0.f;
            sh[h] += w;
            gacc[h][0] += w * x4A.x;
            gacc[h][1] += w * x4A.y;
            gacc[h][2] += w * x4A.z;
            gacc[h][3] += w * x4A.w;
        }
        // rotate pipeline registers
        eB = eC; x4A = x4B; anA = anB;
    }
    // combine the 4 groups
#pragma unroll
    for (int off = 16; off < 64; off <<= 1)
#pragma unroll
        for (int h = 0; h < 4; ++h) {
            sh[h] += __shfl_xor(sh[h], off);
            gacc[h][0] += __shfl_xor(gacc[h][0], off);
            gacc[h][1] += __shfl_xor(gacc[h][1], off);
            gacc[h][2] += __shfl_xor(gacc[h][2], off);
            gacc[h][3] += __shfl_xor(gacc[h][3], off);
        }
    // group g stores head g: Ghat[n][g*64 + q*4 + c]  (1KB coalesced/wave)
    float inv = 1.f / sh[g];
    float4 o4;
    o4.x = gacc[g][0] * inv;
    o4.y = gacc[g][1] * inv;
    o4.z = gacc[g][2] * inv;
    o4.w = gacc[g][3] * inv;
    *(float4*)(Ghat + (size_t)n * 256 + g * 64 + q * 4) = o4;
}

// ---- epilogue GEMM: out[n][o] = relu( sum_j Ghat[n][j] * WeWo[j][o] ) ---
// v2: stage 64 Ghat rows (64KB) in LDS via coalesced float4 loads, then
// 32-lane group handles 8 nodes reading G from LDS (broadcast is free);
// weight regs amortized 8x as before. Kills the 16B-broadcast VMEM storm.
__global__ void k_out(const float* __restrict__ G, const float* __restrict__ WW,
                      const float* __restrict__ X, const float* __restrict__ WnWo,
                      const int* __restrict__ deg, float* __restrict__ out, int N) {
    __shared__ float4 gs[ONODES * 64];       // 64 rows x 256 floats = 64KB
    int tid = threadIdx.x;
    int nb0 = blockIdx.x * ONODES;
    int nrem = N - nb0;
    int nloc = nrem < ONODES ? nrem : ONODES;
    const float4* Gbase = (const float4*)G + (size_t)nb0 * 64;
    for (int i = tid; i < nloc * 64; i += 256)
        gs[i] = Gbase[i];
    __syncthreads();
    int o = tid & 31, grp = tid >> 5;        // 8 groups x 8 nodes
    int t0 = grp * 8;
    float acc[8] = {0.f, 0.f, 0.f, 0.f, 0.f, 0.f, 0.f, 0.f};
    for (int j4 = 0; j4 < 64; ++j4) {
        float w0 = WW[(j4 * 4 + 0) * 32 + o];
        float w1 = WW[(j4 * 4 + 1) * 32 + o];
        float w2 = WW[(j4 * 4 + 2) * 32 + o];
        float w3 = WW[(j4 * 4 + 3) * 32 + o];
#pragma unroll
        for (int t = 0; t < 8; ++t) {
            float4 gv = gs[(t0 + t) * 64 + j4];
            acc[t] += gv.x * w0 + gv.y * w1 + gv.z * w2 + gv.w * w3;
        }
    }
#pragma unroll
    for (int t = 0; t < 8; ++t) {
        int n = nb0 + t0 + t;
        if (n >= N) break;
        float a = acc[t];
        if (deg[n] == 0) {                   // rare: z = X @ (Wn*Wo)
            a = 0.f;
            for (int k = 0; k < INF; ++k)
                a += X[(size_t)n * INF + k] * WnWo[k * DD + o];
        }
        out[(size_t)n * DD + o] = fmaxf(a, 0.f);
    }
}

extern "C" void kernel_launch(void* const* d_in, const int* in_sizes, int n_in,
                              void* d_out, int out_size, void* d_ws, size_t ws_size,
                              hipStream_t stream) {
    const float* node_feats = (const float*)d_in[0];
    const float* edge_feats = (const float*)d_in[1];
    const int*   src        = (const int*)d_in[2];
    const int*   dst        = (const int*)d_in[3];
    const float* Wn         = (const float*)d_in[4];
    const float* We         = (const float*)d_in[5];
    const float* Wa         = (const float*)d_in[6];
    const float* Wo         = (const float*)d_in[7];
    float* out = (float*)d_out;
    int N = in_sizes[0] / INF;
    int E = in_sizes[2];

    char* p = (char*)d_ws;
    auto alloc = [&](size_t bytes) {
        char* r = p;
        p += (bytes + 255) & ~(size_t)255;
        return r;
    };
    float* WnA   = (float*)alloc((size_t)INF * HH * 4);
    float* WnB   = (float*)alloc((size_t)INF * HH * 4);
    float* WeC   = (float*)alloc((size_t)EDF * HH * 4);
    float* WeWo  = (float*)alloc((size_t)EDF * HH * DD * 4);
    float* WnWo  = (float*)alloc((size_t)INF * DD * 4);
    float* an    = (float*)alloc((size_t)N * HH * 4);
    float* bn    = (float*)alloc((size_t)N * HH * 4);
    float* Ghat  = (float*)alloc((size_t)N * 256 * 4);
    int* deg     = (int*)alloc((size_t)N * 4);
    int* offs    = (int*)alloc((size_t)N * 4);
    int* rank    = (int*)alloc((size_t)E * 4);
    int* eids    = (int*)alloc((size_t)E * 4);
    int* partial = (int*)alloc((size_t)NB * 4);
    int* pscan   = (int*)alloc((size_t)NB * 4);

    int chunk = (N + NB - 1) / NB;

    hipLaunchKernelGGL(k_pre, dim3(25), dim3(512), 0, stream,
                       Wn, We, Wa, Wo, WnA, WnB, WeC, WeWo, WnWo);
    hipLaunchKernelGGL(k_nodes, dim3((N + 3) / 4), dim3(256), 0, stream,
                       node_feats, WnA, WnB, an, bn, N);
    hipLaunchKernelGGL(k_init, dim3((N + 255) / 256), dim3(256), 0, stream, deg, N);
    hipLaunchKernelGGL(k_hist, dim3((E + 255) / 256), dim3(256), 0, stream,
                       dst, deg, rank, E);
    hipLaunchKernelGGL(k_scan1, dim3(NB), dim3(256), 0, stream, deg, partial, N, chunk);
    hipLaunchKernelGGL(k_scan2, dim3(1), dim3(NB), 0, stream, partial, pscan);
    hipLaunchKernelGGL(k_scan3, dim3(NB), dim3(256), 0, stream, deg, pscan, offs, N, chunk);
    hipLaunchKernelGGL(k_eids, dim3((E + 255) / 256), dim3(256), 0, stream,
                       dst, offs, rank, eids, E);
    hipLaunchKernelGGL(k_agg, dim3((N + 3) / 4), dim3(256), 0, stream,
                       edge_feats, an, bn, WeC, src, eids, offs, deg, Ghat, N);
    hipLaunchKernelGGL(k_out, dim3((N + ONODES - 1) / ONODES), dim3(256), 0, stream,
                       Ghat, WeWo, node_feats, WnWo, deg, out, N);
}